// Round 1
// baseline (11.825 us; speedup 1.0000x reference)
//
#include <hip/hip_runtime.h>
#include <cstddef>

#define BB   16
#define LL   4096
#define DD   512
#define OUTN 512
#define OCHUNK 64   // outputs per block (grid.y = OUTN/OCHUNK = 8)

__global__ __launch_bounds__(256) void fluct_kernel(
    const float* __restrict__ X,          // (B, L, D)
    const int*   __restrict__ mask,       // (B, L)
    const float* __restrict__ alpha_logits, // (2,)
    const float* __restrict__ W,          // (OUT, D)
    const float* __restrict__ bias,       // (OUT,)
    float*       __restrict__ out)        // (B, OUT)
{
    const int b   = blockIdx.x;
    const int tid = threadIdx.x;

    __shared__ float z_s[DD];
    __shared__ int   wsum[4];

    // ---- Phase 1: len = sum(mask[b, 1:L]) ----
    const int* mrow = mask + (size_t)b * LL;
    int local = 0;
    for (int j = 1 + tid; j < LL; j += 256) local += mrow[j];
    #pragma unroll
    for (int off = 32; off > 0; off >>= 1) local += __shfl_down(local, off, 64);
    if ((tid & 63) == 0) wsum[tid >> 6] = local;
    __syncthreads();
    const int len = wsum[0] + wsum[1] + wsum[2] + wsum[3];

    // ---- Phase 2: z into LDS (telescoped) ----
    // S[j] = X[b, 1+j, :]
    // len==0: z=0 ; len==1: z=S[0] ;
    // len>=2: z = (a1*(S[len-1]-S[0]) + a2*(S[len-1]+S[len-2]-S[0]-S[1])) / (len-1)
    const float l0 = alpha_logits[0], l1 = alpha_logits[1];
    const float mx = fmaxf(l0, l1);
    const float e0 = __expf(l0 - mx), e1 = __expf(l1 - mx);
    const float inv = 1.0f / (e0 + e1);
    const float a1 = e0 * inv, a2 = e1 * inv;

    const float* Xb = X + (size_t)b * LL * DD;
    #pragma unroll
    for (int k = 0; k < 2; ++k) {
        const int d = tid + 256 * k;
        float zv = 0.0f;
        if (len == 1) {
            zv = Xb[DD + d];                       // S[0]
        } else if (len >= 2) {
            const float s0  = Xb[DD + d];                       // S[0]   = X[b,1]
            const float s1  = Xb[2 * DD + d];                   // S[1]   = X[b,2]
            const float sl1 = Xb[(size_t)len * DD + d];         // S[len-1] = X[b,len]
            const float sl2 = Xb[(size_t)(len - 1) * DD + d];   // S[len-2] = X[b,len-1]
            const float denom = (float)(len - 1);
            zv = (a1 * (sl1 - s0) + a2 * (sl1 + sl2 - s0 - s1)) / denom;
        }
        z_s[d] = zv;
    }
    __syncthreads();

    // ---- Phase 3: out[b, o] = z . W[o,:] + bias[o] ----
    // 64 outputs per block, 4 threads per output (128 d-elems each), shfl_xor reduce.
    const int o_local = tid >> 2;   // 0..63
    const int sub     = tid & 3;    // 0..3
    const int o       = blockIdx.y * OCHUNK + o_local;

    const float4* Wrow = (const float4*)(W + (size_t)o * DD);  // 128 float4 per row
    const float4* z4   = (const float4*)z_s;

    float acc = 0.0f;
    #pragma unroll 8
    for (int i = 0; i < 32; ++i) {
        const float4 w  = Wrow[sub * 32 + i];
        const float4 zv = z4[sub * 32 + i];
        acc += w.x * zv.x + w.y * zv.y + w.z * zv.z + w.w * zv.w;
    }
    acc += __shfl_xor(acc, 1, 64);
    acc += __shfl_xor(acc, 2, 64);
    if (sub == 0) out[(size_t)b * OUTN + o] = acc + bias[o];
}

extern "C" void kernel_launch(void* const* d_in, const int* in_sizes, int n_in,
                              void* d_out, int out_size, void* d_ws, size_t ws_size,
                              hipStream_t stream) {
    const float* X            = (const float*)d_in[0];
    const int*   attn_mask    = (const int*)d_in[1];
    const float* alpha_logits = (const float*)d_in[2];
    const float* W            = (const float*)d_in[3];
    const float* bias         = (const float*)d_in[4];
    float* out = (float*)d_out;

    dim3 grid(BB, OUTN / OCHUNK);
    fluct_kernel<<<grid, 256, 0, stream>>>(X, attn_mask, alpha_logits, W, bias, out);
}

// Round 2
// 9.611 us; speedup vs baseline: 1.2303x; 1.2303x over previous
//
#include <hip/hip_runtime.h>
#include <cstddef>

#define BB   16
#define LL   4096
#define DD   512
#define OUTN 512
#define OCHUNK 32   // outputs per block (grid.y = OUTN/OCHUNK = 16)

__global__ __launch_bounds__(256) void fluct_kernel(
    const float* __restrict__ X,            // (B, L, D)
    const int*   __restrict__ mask,         // (B, L)
    const float* __restrict__ alpha_logits, // (2,)
    const float* __restrict__ W,            // (OUT, D)
    const float* __restrict__ bias,         // (OUT,)
    float*       __restrict__ out)          // (B, OUT)
{
    const int b   = blockIdx.x;
    const int tid = threadIdx.x;

    const int o_local = tid >> 3;   // 0..31
    const int sub     = tid & 7;    // 0..7  (8 threads per output)
    const int o       = blockIdx.y * OCHUNK + o_local;

    __shared__ float z_s[DD];
    __shared__ int   wsum[4];

    // ---- Phase 0: prefetch W into registers (no dependency on len; hides
    //      its HBM latency under the mask-reduce + X-gather phases) ----
    const float4* Wrow = (const float4*)(W + (size_t)o * DD);  // 128 float4 per row
    float4 w[16];
    #pragma unroll
    for (int i = 0; i < 16; ++i) w[i] = Wrow[i * 8 + sub];

    // ---- Phase 1: len = sum(mask[b, 1:L]) ----
    const int*  mrow = mask + (size_t)b * LL;
    const int4* m4   = (const int4*)mrow;
    int local = 0;
    #pragma unroll
    for (int k = 0; k < 4; ++k) {          // 1024 int4 across 256 threads
        const int4 v = m4[tid + 256 * k];
        local += v.x + v.y + v.z + v.w;
    }
    #pragma unroll
    for (int off = 32; off; off >>= 1) local += __shfl_down(local, off, 64);
    if ((tid & 63) == 0) wsum[tid >> 6] = local;
    const int m0 = mrow[0];                 // uniform (scalar) load, exclude j=0
    __syncthreads();
    const int len = wsum[0] + wsum[1] + wsum[2] + wsum[3] - m0;

    // ---- softmax(alpha_logits) ----
    const float l0 = alpha_logits[0], l1 = alpha_logits[1];
    const float mx = fmaxf(l0, l1);
    const float e0 = __expf(l0 - mx), e1 = __expf(l1 - mx);
    const float inv = 1.0f / (e0 + e1);
    const float a1 = e0 * inv, a2 = e1 * inv;

    // ---- Phase 2: z into LDS (telescoped) ----
    // S[j] = X[b, 1+j, :]
    // len==0: z=0 ; len==1: z=S[0] ;
    // len>=2: z = (a1*(S[len-1]-S[0]) + a2*(S[len-1]+S[len-2]-S[0]-S[1])) / (len-1)
    const float* Xb = X + (size_t)b * LL * DD;
    #pragma unroll
    for (int k = 0; k < 2; ++k) {
        const int d = tid + 256 * k;
        float zv = 0.0f;
        if (len == 1) {
            zv = Xb[DD + d];                                    // S[0]
        } else if (len >= 2) {
            const float s0  = Xb[DD + d];                       // S[0]     = X[b,1]
            const float s1  = Xb[2 * DD + d];                   // S[1]     = X[b,2]
            const float sl1 = Xb[(size_t)len * DD + d];         // S[len-1] = X[b,len]
            const float sl2 = Xb[(size_t)(len - 1) * DD + d];   // S[len-2] = X[b,len-1]
            zv = (a1 * (sl1 - s0) + a2 * (sl1 + sl2 - s0 - s1)) / (float)(len - 1);
        }
        z_s[d] = zv;
    }
    __syncthreads();

    // ---- Phase 3: out[b, o] = z . W[o,:] + bias[o] ----
    // z4 reads are uniform per 8-lane group -> LDS broadcast, conflict-free.
    const float4* z4 = (const float4*)z_s;
    float acc = 0.0f;
    #pragma unroll
    for (int i = 0; i < 16; ++i) {
        const float4 zv = z4[i * 8 + sub];
        acc += w[i].x * zv.x + w[i].y * zv.y + w[i].z * zv.z + w[i].w * zv.w;
    }
    acc += __shfl_xor(acc, 1, 64);
    acc += __shfl_xor(acc, 2, 64);
    acc += __shfl_xor(acc, 4, 64);
    if (sub == 0) out[(size_t)b * OUTN + o] = acc + bias[o];
}

extern "C" void kernel_launch(void* const* d_in, const int* in_sizes, int n_in,
                              void* d_out, int out_size, void* d_ws, size_t ws_size,
                              hipStream_t stream) {
    const float* X            = (const float*)d_in[0];
    const int*   attn_mask    = (const int*)d_in[1];
    const float* alpha_logits = (const float*)d_in[2];
    const float* W            = (const float*)d_in[3];
    const float* bias         = (const float*)d_in[4];
    float* out = (float*)d_out;

    dim3 grid(BB, OUTN / OCHUNK);
    fluct_kernel<<<grid, 256, 0, stream>>>(X, attn_mask, alpha_logits, W, bias, out);
}